// Round 3
// baseline (136.792 us; speedup 1.0000x reference)
//
#include <hip/hip_runtime.h>
#include <hip/hip_bf16.h>
#include <stdint.h>

// SVM RBF layer: out[j] = b + sum_i a[i]*Y[i]*exp(-g*max(||x_i||^2+||z_j||^2-2*x_i.z_j, 0))
// N=8192 support vectors, M=4096 query points, d=512.
#define GAMMA_F 0.001953125f
// -GAMMA * log2(e), so exp(-g*d) == exp2(C2EXP * d)
#define C2EXP (-0.0028179443441958f)

static constexpr int N_SV = 8192;
static constexpr int M_Q  = 4096;
static constexpr int DIM  = 512;

typedef __bf16 bf16x8 __attribute__((ext_vector_type(8)));
typedef float  f32x4  __attribute__((ext_vector_type(4)));

#define GLB const __attribute__((address_space(1))) void
#define LDS __attribute__((address_space(3))) void

// ---------------- prep: fp32 -> bf16 + row norms + weights + out=b ----------
// 4 waves per block, one row per wave. r < N_SV: X row; else: Z row (also
// writes out[j] = b, replacing the separate init kernel).
__global__ __launch_bounds__(256) void svm_prep(
    const float* __restrict__ Z, const float* __restrict__ X,
    const float* __restrict__ Y, const float* __restrict__ a,
    const float* __restrict__ b,
    __bf16* __restrict__ Xb, __bf16* __restrict__ Zb,
    float* __restrict__ xn, float* __restrict__ zn, float* __restrict__ w,
    float* __restrict__ out)
{
    const int r = blockIdx.x * 4 + (threadIdx.x >> 6);
    const int t = threadIdx.x & 63;   // lane; handles elems 4t..4t+3 and 256+4t..
    const float* src;
    __bf16* dst;
    if (r < N_SV) { src = X + (size_t)r * DIM; dst = Xb + (size_t)r * DIM; }
    else          { src = Z + (size_t)(r - N_SV) * DIM; dst = Zb + (size_t)(r - N_SV) * DIM; }

    const float4* row4 = (const float4*)src;
    float4 v0 = row4[t];        // elems 4t .. 4t+3      (coalesced)
    float4 v1 = row4[t + 64];   // elems 256+4t .. +3    (coalesced)

    float s = v0.x*v0.x + v0.y*v0.y + v0.z*v0.z + v0.w*v0.w
            + v1.x*v1.x + v1.y*v1.y + v1.z*v1.z + v1.w*v1.w;

    __bf16 h0[4] = {(__bf16)v0.x, (__bf16)v0.y, (__bf16)v0.z, (__bf16)v0.w};
    __bf16 h1[4] = {(__bf16)v1.x, (__bf16)v1.y, (__bf16)v1.z, (__bf16)v1.w};
    uint2 b0, b1;
    __builtin_memcpy(&b0, h0, 8);
    __builtin_memcpy(&b1, h1, 8);
    ((uint2*)dst)[t]      = b0;
    ((uint2*)dst)[t + 64] = b1;

    #pragma unroll
    for (int o = 32; o > 0; o >>= 1) s += __shfl_xor(s, o);

    if (t == 0) {
        if (r < N_SV) { xn[r] = s; w[r] = a[r] * Y[r]; }
        else          { int m = r - N_SV; zn[m] = s; out[m] = b[0]; }
    }
}

// ---------------- main fused tile kernel ------------------------------------
// 128x128 output tile, BK=32, 4 waves in 2x2, 4x4 frags of mfma 16x16x32 bf16.
// Single-barrier double-buffered K-loop (T3-minimal): stage tile t+1 while
// computing tile t. LDS XOR-swizzled (both sides, rule 21): logical chunk lc
// (16B) of row r lives at phys chunk lc ^ ((r>>1)&3) -> conflict-free b128.
__global__ __launch_bounds__(256) void svm_main(
    const __bf16* __restrict__ Xb, const __bf16* __restrict__ Zb,
    const float* __restrict__ xn, const float* __restrict__ zn,
    const float* __restrict__ w, float* __restrict__ out)
{
    __shared__ __bf16 As[2 * 128 * 32];   // 2 x 8 KB, rows = i, cols = k
    __shared__ __bf16 Bs[2 * 128 * 32];   // 2 x 8 KB, rows = j, cols = k

    const int tid  = threadIdx.x;      // 0..255
    const int lane = tid & 63;
    const int wid  = tid >> 6;         // 0..3
    const int wr   = wid >> 1;         // wave row (i)
    const int wc   = wid & 1;          // wave col (j)

    const int iBase = blockIdx.y * 128;
    const int jBase = blockIdx.x * 128;

    f32x4 acc[4][4];
    #pragma unroll
    for (int m = 0; m < 4; ++m)
        #pragma unroll
        for (int n = 0; n < 4; ++n)
            acc[m][n] = (f32x4)(0.0f);

    // staging: LDS dest linear (required); source chunk inverse-swizzled.
    // phys (row=tid>>2 (+64q), pchunk=tid&3) holds logical chunk pchunk^((row>>1)&3).
    const int srow   = tid >> 2;                         // 0..63
    const int schunk = (tid & 3) ^ ((tid >> 3) & 3);     // logical chunk to fetch
    const int sce    = schunk * 8;                       // element offset in row

    // fragment read: logical (row=base+lrow, chunk=lane>>4) at phys chunk ^ rsw
    const int lrow = lane & 15;
    const int rsw  = (lrow >> 1) & 3;
    const int lkb  = ((lane >> 4) ^ rsw) * 16;           // swizzled byte-in-row

    auto stage = [&](int buf, int k0) {
        #pragma unroll
        for (int q = 0; q < 2; ++q) {
            const int row = q * 64 + srow;
            const __bf16* sa = Xb + (size_t)(iBase + row) * DIM + k0 + sce;
            __builtin_amdgcn_global_load_lds((GLB*)sa,
                (LDS*)((char*)As + buf * 8192 + q * 4096 + tid * 16), 16, 0, 0);
            const __bf16* sb = Zb + (size_t)(jBase + row) * DIM + k0 + sce;
            __builtin_amdgcn_global_load_lds((GLB*)sb,
                (LDS*)((char*)Bs + buf * 8192 + q * 4096 + tid * 16), 16, 0, 0);
        }
    };

    stage(0, 0);
    __syncthreads();   // vmcnt(0) drain: buf0 ready

    #pragma unroll
    for (int kt = 0; kt < 16; ++kt) {
        const int buf = kt & 1;
        if (kt < 15) stage(buf ^ 1, (kt + 1) * 32);   // prefetch next tile

        bf16x8 af[4], bfr[4];
        #pragma unroll
        for (int m = 0; m < 4; ++m)
            af[m] = *(const bf16x8*)((const char*)As + buf * 8192
                        + (wr * 64 + m * 16 + lrow) * 64 + lkb);
        #pragma unroll
        for (int n = 0; n < 4; ++n)
            bfr[n] = *(const bf16x8*)((const char*)Bs + buf * 8192
                        + (wc * 64 + n * 16 + lrow) * 64 + lkb);

        #pragma unroll
        for (int m = 0; m < 4; ++m)
            #pragma unroll
            for (int n = 0; n < 4; ++n)
                acc[m][n] = __builtin_amdgcn_mfma_f32_16x16x32_bf16(
                    af[m], bfr[n], acc[m][n], 0, 0, 0);

        __syncthreads();   // next tile staged; frag data already in regs
    }

    // ---- fused RBF epilogue ----
    // C frag (16x16x32): col = lane&15, row = (lane>>4)*4 + reg  [m89]
    const int rg   = lane >> 4;
    const int lcol = lane & 15;

    float wv[16], xv[16];
    #pragma unroll
    for (int m = 0; m < 4; ++m)
        #pragma unroll
        for (int r = 0; r < 4; ++r) {
            const int i = iBase + wr * 64 + m * 16 + rg * 4 + r;
            wv[m * 4 + r] = w[i];
            xv[m * 4 + r] = xn[i];
        }

    #pragma unroll
    for (int n = 0; n < 4; ++n) {
        const int j = jBase + wc * 64 + n * 16 + lcol;
        const float znj = zn[j];
        float cs = 0.0f;
        #pragma unroll
        for (int m = 0; m < 4; ++m)
            #pragma unroll
            for (int r = 0; r < 4; ++r) {
                float d = xv[m * 4 + r] + znj - 2.0f * acc[m][n][r];
                d = fmaxf(d, 0.0f);
                cs += wv[m * 4 + r] * exp2f(C2EXP * d);
            }
        cs += __shfl_xor(cs, 16);
        cs += __shfl_xor(cs, 32);
        if (lane < 16) atomicAdd(out + j, cs);
    }
}

// ---------------- launch -----------------------------------------------------
extern "C" void kernel_launch(void* const* d_in, const int* in_sizes, int n_in,
                              void* d_out, int out_size, void* d_ws, size_t ws_size,
                              hipStream_t stream)
{
    const float* Z = (const float*)d_in[0];   // inputs [4096, 512]
    const float* X = (const float*)d_in[1];   // X      [8192, 512]
    const float* Y = (const float*)d_in[2];   // Y      [8192, 1]
    const float* a = (const float*)d_in[3];   // a      [8192, 1]
    const float* b = (const float*)d_in[4];   // b      [1, 1]
    float* out = (float*)d_out;               // [4096, 1]

    char* ws = (char*)d_ws;
    __bf16* Xb = (__bf16*)ws;                                   // 8 MB
    __bf16* Zb = (__bf16*)(ws + 8ull * 1024 * 1024);            // 4 MB
    float*  xn = (float*)(ws + 12ull * 1024 * 1024);            // 32 KB
    float*  zn = xn + N_SV;                                     // 16 KB
    float*  w  = zn + M_Q;                                      // 32 KB

    svm_prep<<<(N_SV + M_Q) / 4, 256, 0, stream>>>(Z, X, Y, a, b, Xb, Zb, xn, zn, w, out);
    svm_main<<<dim3(M_Q / 128, N_SV / 128), 256, 0, stream>>>(Xb, Zb, xn, zn, w, out);
}

// Round 5
// 119.898 us; speedup vs baseline: 1.1409x; 1.1409x over previous
//
#include <hip/hip_runtime.h>
#include <hip/hip_bf16.h>
#include <stdint.h>

// SVM RBF layer: out[j] = b + sum_i a[i]*Y[i]*exp(-g*max(||x_i||^2+||z_j||^2-2*x_i.z_j, 0))
// N=8192 support vectors, M=4096 query points, d=512.
#define C2EXP (-0.0028179443441958f)   // -GAMMA * log2(e)

static constexpr int N_SV = 8192;
static constexpr int M_Q  = 4096;
static constexpr int DIM  = 512;

typedef __bf16 bf16x8 __attribute__((ext_vector_type(8)));
typedef float  f32x4  __attribute__((ext_vector_type(4)));

#define GLB const __attribute__((address_space(1))) void
#define LDS __attribute__((address_space(3))) void

// ---------------- prep: fp32 -> bf16 + row norms + weights + out=b ----------
__global__ __launch_bounds__(256) void svm_prep(
    const float* __restrict__ Z, const float* __restrict__ X,
    const float* __restrict__ Y, const float* __restrict__ a,
    const float* __restrict__ b,
    __bf16* __restrict__ Xb, __bf16* __restrict__ Zb,
    float* __restrict__ xn, float* __restrict__ zn, float* __restrict__ w,
    float* __restrict__ out)
{
    const int r = blockIdx.x * 4 + (threadIdx.x >> 6);
    const int t = threadIdx.x & 63;
    const float* src;
    __bf16* dst;
    if (r < N_SV) { src = X + (size_t)r * DIM; dst = Xb + (size_t)r * DIM; }
    else          { src = Z + (size_t)(r - N_SV) * DIM; dst = Zb + (size_t)(r - N_SV) * DIM; }

    const float4* row4 = (const float4*)src;
    float4 v0 = row4[t];
    float4 v1 = row4[t + 64];

    float s = v0.x*v0.x + v0.y*v0.y + v0.z*v0.z + v0.w*v0.w
            + v1.x*v1.x + v1.y*v1.y + v1.z*v1.z + v1.w*v1.w;

    __bf16 h0[4] = {(__bf16)v0.x, (__bf16)v0.y, (__bf16)v0.z, (__bf16)v0.w};
    __bf16 h1[4] = {(__bf16)v1.x, (__bf16)v1.y, (__bf16)v1.z, (__bf16)v1.w};
    uint2 b0, b1;
    __builtin_memcpy(&b0, h0, 8);
    __builtin_memcpy(&b1, h1, 8);
    ((uint2*)dst)[t]      = b0;
    ((uint2*)dst)[t + 64] = b1;

    #pragma unroll
    for (int o = 32; o > 0; o >>= 1) s += __shfl_xor(s, o);

    if (t == 0) {
        if (r < N_SV) { xn[r] = s; w[r] = a[r] * Y[r]; }
        else          { int m = r - N_SV; zn[m] = s; out[m] = b[0]; }
    }
}

// ---------------- main: 256x256 tile, 8 waves, 2-phase/K-tile pipeline ------
// LDS is fragment-linear: 1024-B blocks, block = one 16x32 MFMA fragment in
// exact lane order (lane l holds row l&15, k (l>>4)*8). global_load_lds dest
// is base+tid*16 (linear, required); the per-lane GLOBAL address does the
// fragment gather (16 x 64B segments, cache-line coalesced). ds_read is then
// base+lane*16: contiguous, zero bank conflicts, immediate offsets.
// Layout: [buf(2)][A 16KB | B 16KB]; A block rb in [0,16) = tile rows rb*16..
// Pipeline (T3+T4): stage A(t+1) in ph0, B(t+2) in ph1 (slot freed previous
// phase, barrier between); s_waitcnt vmcnt(2) once per K-tile (never 0 until
// the tail). Raw s_barrier (no vmcnt(0) drain), lgkmcnt(0)+sched_barrier
// before MFMA (rule 18), setprio around MFMA cluster (T5).
__global__ __launch_bounds__(512, 2) void svm_main(
    const __bf16* __restrict__ Xb, const __bf16* __restrict__ Zb,
    const float* __restrict__ xn, const float* __restrict__ zn,
    const float* __restrict__ w, float* __restrict__ out)
{
    __shared__ char Sh[65536];

    const int tid  = threadIdx.x;      // 0..511
    const int lane = tid & 63;
    const int wid  = tid >> 6;         // 0..7
    const int wr   = wid >> 2;         // M-group {0,1}  -> rows wr*128
    const int wc   = wid & 3;          // N-group {0..3} -> cols wc*64

    const int iBase = blockIdx.y * 256;
    const int jBase = blockIdx.x * 256;

    f32x4 acc[8][4];
    #pragma unroll
    for (int m = 0; m < 8; ++m)
        #pragma unroll
        for (int n = 0; n < 4; ++n)
            acc[m][n] = (f32x4)(0.0f);

    // stage one operand half (16 KB = 16 fragment blocks, 2 calls x 8 waves)
    auto stage = [&](const __bf16* Mb, int rowBase, int t, int op) {
        char* dst0 = (char*)Sh + ((t & 1) * 32768) + op * 16384 + tid * 16;
        const __bf16* src0 = Mb
            + (size_t)(rowBase + (lane & 15)) * DIM + t * 32 + (lane >> 4) * 8;
        #pragma unroll
        for (int s = 0; s < 2; ++s) {
            const __bf16* src = src0 + (size_t)((s * 8 + wid) * 16) * DIM;
            __builtin_amdgcn_global_load_lds((GLB*)src, (LDS*)(dst0 + s * 8192),
                                             16, 0, 0);
        }
    };

    // ---- prologue: A0, B0, B1 in flight; wait A0,B0 (leave B1 flying) ----
    stage(Xb, iBase, 0, 0);
    stage(Zb, jBase, 0, 1);
    stage(Zb, jBase, 1, 1);
    asm volatile("s_waitcnt vmcnt(2)" ::: "memory");
    __builtin_amdgcn_s_barrier();

    bf16x8 af[4], bfr[4];

    #pragma unroll
    for (int t = 0; t < 16; ++t) {
        const int buf = t & 1;
        const char* Ab = (const char*)Sh + buf * 32768 + lane * 16;

        // ---- ph0: read A m0-3 + B n0-3; stage A(t+1) into buf^1 ----
        #pragma unroll
        for (int m = 0; m < 4; ++m)
            af[m] = *(const bf16x8*)(Ab + (wr * 8 + m) * 1024);
        #pragma unroll
        for (int n = 0; n < 4; ++n)
            bfr[n] = *(const bf16x8*)(Ab + 16384 + (wc * 4 + n) * 1024);
        if (t + 1 < 16) stage(Xb, iBase, t + 1, 0);
        __builtin_amdgcn_s_barrier();
        asm volatile("s_waitcnt lgkmcnt(0)" ::: "memory");
        __builtin_amdgcn_sched_barrier(0);
        __builtin_amdgcn_s_setprio(1);
        #pragma unroll
        for (int m = 0; m < 4; ++m)
            #pragma unroll
            for (int n = 0; n < 4; ++n)
                acc[m][n] = __builtin_amdgcn_mfma_f32_16x16x32_bf16(
                    af[m], bfr[n], acc[m][n], 0, 0, 0);
        __builtin_amdgcn_s_setprio(0);
        __builtin_amdgcn_s_barrier();

        // ---- ph1: read A m4-7 (B c-slice reused from regs); stage B(t+2) ----
        #pragma unroll
        for (int m = 0; m < 4; ++m)
            af[m] = *(const bf16x8*)(Ab + (wr * 8 + 4 + m) * 1024);
        if (t + 2 < 16) stage(Zb, jBase, t + 2, 1);
        __builtin_amdgcn_s_barrier();
        asm volatile("s_waitcnt lgkmcnt(0)" ::: "memory");
        __builtin_amdgcn_sched_barrier(0);
        __builtin_amdgcn_s_setprio(1);
        #pragma unroll
        for (int m = 0; m < 4; ++m)
            #pragma unroll
            for (int n = 0; n < 4; ++n)
                acc[4 + m][n] = __builtin_amdgcn_mfma_f32_16x16x32_bf16(
                    af[m], bfr[n], acc[4 + m][n], 0, 0, 0);
        __builtin_amdgcn_s_setprio(0);

        // tile-boundary counted wait: newest half (2 loads) may stay in flight
        if (t < 14) {
            asm volatile("s_waitcnt vmcnt(2)" ::: "memory");
            __builtin_amdgcn_s_barrier();
        } else if (t == 14) {
            asm volatile("s_waitcnt vmcnt(0)" ::: "memory");
            __builtin_amdgcn_s_barrier();
        }
    }

    // ---- fused RBF epilogue ----
    // C frag (16x16x32): col = lane&15, row = (lane>>4)*4 + reg  [m89]
    const int rg   = lane >> 4;
    const int lcol = lane & 15;

    float znv[4];
    #pragma unroll
    for (int n = 0; n < 4; ++n)
        znv[n] = zn[jBase + wc * 64 + n * 16 + lcol];

    float cs[4] = {0.f, 0.f, 0.f, 0.f};
    #pragma unroll
    for (int m = 0; m < 8; ++m) {
        float wv[4], xv[4];
        #pragma unroll
        for (int r = 0; r < 4; ++r) {
            const int i = iBase + wr * 128 + m * 16 + rg * 4 + r;
            wv[r] = w[i];
            xv[r] = xn[i];
        }
        #pragma unroll
        for (int n = 0; n < 4; ++n)
            #pragma unroll
            for (int r = 0; r < 4; ++r) {
                float d = xv[r] + znv[n] - 2.0f * acc[m][n][r];
                d = fmaxf(d, 0.0f);
                cs[n] += wv[r] * exp2f(C2EXP * d);
            }
    }

    #pragma unroll
    for (int n = 0; n < 4; ++n) {
        const int j = jBase + wc * 64 + n * 16 + lcol;
        float c = cs[n];
        c += __shfl_xor(c, 16);
        c += __shfl_xor(c, 32);
        if (lane < 16) atomicAdd(out + j, c);
    }
}

// ---------------- launch -----------------------------------------------------
extern "C" void kernel_launch(void* const* d_in, const int* in_sizes, int n_in,
                              void* d_out, int out_size, void* d_ws, size_t ws_size,
                              hipStream_t stream)
{
    const float* Z = (const float*)d_in[0];   // inputs [4096, 512]
    const float* X = (const float*)d_in[1];   // X      [8192, 512]
    const float* Y = (const float*)d_in[2];   // Y      [8192, 1]
    const float* a = (const float*)d_in[3];   // a      [8192, 1]
    const float* b = (const float*)d_in[4];   // b      [1, 1]
    float* out = (float*)d_out;               // [4096, 1]

    char* ws = (char*)d_ws;
    __bf16* Xb = (__bf16*)ws;                                   // 8 MB
    __bf16* Zb = (__bf16*)(ws + 8ull * 1024 * 1024);            // 4 MB
    float*  xn = (float*)(ws + 12ull * 1024 * 1024);            // 32 KB
    float*  zn = xn + N_SV;                                     // 16 KB
    float*  w  = zn + M_Q;                                      // 32 KB

    svm_prep<<<(N_SV + M_Q) / 4, 256, 0, stream>>>(Z, X, Y, a, b, Xb, Zb, xn, zn, w, out);
    svm_main<<<dim3(M_Q / 256, N_SV / 256), 512, 0, stream>>>(Xb, Zb, xn, zn, w, out);
}

// Round 7
// 111.260 us; speedup vs baseline: 1.2295x; 1.0776x over previous
//
#include <hip/hip_runtime.h>
#include <hip/hip_bf16.h>
#include <stdint.h>

// SVM RBF layer: out[j] = b + sum_i a[i]*Y[i]*exp(-g*max(||x_i||^2+||z_j||^2-2*x_i.z_j, 0))
// N=8192 support vectors, M=4096 query points, d=512.
#define C2EXP (-0.0028179443441958f)   // -GAMMA * log2(e)

static constexpr int N_SV = 8192;
static constexpr int M_Q  = 4096;
static constexpr int DIM  = 512;
static constexpr int NP_A = N_SV / 16;   // 512 A panels (16 rows each)
static constexpr int NP_B = M_Q / 16;    // 256 B panels
static constexpr int NKT  = DIM / 32;    // 16 K-tiles

typedef __bf16 bf16x8 __attribute__((ext_vector_type(8)));
typedef float  f32x4  __attribute__((ext_vector_type(4)));

#define GLB const __attribute__((address_space(1))) void
#define LDS __attribute__((address_space(3))) void

// ---------------- prep v2: panel blocks -> fragment-block layout ------------
// One 256-thread block per 16-row panel. Output layout: Xp/Zp as 1-KB
// fragment blocks [kt][panel]: block (kt,p) holds the 16x32 MFMA fragment of
// panel p, K-slice kt, in exact lane order (lane l: row l&15, k (l>>4)*8..+7,
// bytes l*16). Main then reads 16-KB CONTIGUOUS chunks per (tile,kt).
// Also: per-row norms (shfl + cross-wave LDS reduce), w = a*Y, out = b.
__global__ __launch_bounds__(256) void svm_prep(
    const float* __restrict__ Z, const float* __restrict__ X,
    const float* __restrict__ Y, const float* __restrict__ a,
    const float* __restrict__ b,
    __bf16* __restrict__ Xp, __bf16* __restrict__ Zp,
    float* __restrict__ xn, float* __restrict__ zn, float* __restrict__ w,
    float* __restrict__ out)
{
    __shared__ float part[4][16];

    const int tid  = threadIdx.x;
    const int lane = tid & 63;
    const int wv   = tid >> 6;          // wave 0..3, owns kt = wv*4 .. wv*4+3
    const int pb   = blockIdx.x;        // 0..767
    const bool isA = (pb < NP_A);
    const int p    = isA ? pb : pb - NP_A;
    const float* src = (isA ? X : Z) + (size_t)p * 16 * DIM;
    __bf16* dst  = isA ? Xp : Zp;
    const int np = isA ? NP_A : NP_B;

    const int row = lane & 15;          // row within panel
    const int ch  = lane >> 4;          // k-chunk 0..3 (8 elems each)

    float s = 0.0f;
    #pragma unroll
    for (int f = 0; f < 4; ++f) {
        const int kt = wv * 4 + f;
        const float4* rp = (const float4*)(src + (size_t)row * DIM + kt * 32 + ch * 8);
        float4 v0 = rp[0], v1 = rp[1];
        s += v0.x*v0.x + v0.y*v0.y + v0.z*v0.z + v0.w*v0.w
           + v1.x*v1.x + v1.y*v1.y + v1.z*v1.z + v1.w*v1.w;
        __bf16 h[8] = {(__bf16)v0.x, (__bf16)v0.y, (__bf16)v0.z, (__bf16)v0.w,
                       (__bf16)v1.x, (__bf16)v1.y, (__bf16)v1.z, (__bf16)v1.w};
        uint4 bits;
        __builtin_memcpy(&bits, h, 16);
        *(uint4*)((char*)dst + (((size_t)kt * np + p) << 10) + lane * 16) = bits;
    }

    // lanes {l, l^16, l^32, l^48} share a row and tile its 128 cols
    s += __shfl_xor(s, 16);
    s += __shfl_xor(s, 32);
    if (lane < 16) part[wv][lane] = s;
    __syncthreads();

    if (tid < 16) {
        const float t = part[0][tid] + part[1][tid] + part[2][tid] + part[3][tid];
        const int r = p * 16 + tid;
        if (isA) { xn[r] = t; w[r] = a[r] * Y[r]; }
        else     { zn[r] = t; out[r] = b[0]; }
    }
}

// ---------------- main: 256x256 tile, 8 waves, 2-phase/K-tile pipeline ------
// LDS fragment-linear (1-KB blocks = one 16x32 MFMA fragment in lane order).
// Global side now CONTIGUOUS: stage reads a 16-KB block from the permuted
// layout (base + tid*16), LDS dest linear, ds_read linear -> zero bank
// conflicts, ideal coalescing, no hot-loop swizzle math.
// Pipeline (T3+T4): stage A(t+1) in ph0, B(t+2) in ph1; vmcnt(2) once per
// K-tile (never 0 until tail). Raw s_barrier, lgkmcnt(0)+sched_barrier before
// MFMA (rule 18), setprio around MFMA (T5).
__global__ __launch_bounds__(512, 2) void svm_main(
    const __bf16* __restrict__ Xp, const __bf16* __restrict__ Zp,
    const float* __restrict__ xn, const float* __restrict__ zn,
    const float* __restrict__ w, float* __restrict__ out)
{
    __shared__ char Sh[65536];

    const int tid  = threadIdx.x;      // 0..511
    const int lane = tid & 63;
    const int wid  = tid >> 6;         // 0..7
    const int wr   = wid >> 2;         // M-group {0,1}  -> rows wr*128
    const int wc   = wid & 3;          // N-group {0..3} -> cols wc*64

    const int iBase = blockIdx.y * 256;
    const int jBase = blockIdx.x * 256;
    const int pbA   = blockIdx.y * 16;  // first A panel of this tile
    const int pbB   = blockIdx.x * 16;  // first B panel

    f32x4 acc[8][4];
    #pragma unroll
    for (int m = 0; m < 8; ++m)
        #pragma unroll
        for (int n = 0; n < 4; ++n)
            acc[m][n] = (f32x4)(0.0f);

    // stage one operand K-tile: 16 KB contiguous global -> linear LDS
    auto stage = [&](const __bf16* Mp, int pb16, int t, int op, int np) {
        char* dst0 = (char*)Sh + ((t & 1) * 32768) + op * 16384 + tid * 16;
        const char* s0 = (const char*)Mp + (((size_t)t * np + pb16) << 10) + tid * 16;
        __builtin_amdgcn_global_load_lds((GLB*)s0, (LDS*)dst0, 16, 0, 0);
        __builtin_amdgcn_global_load_lds((GLB*)(s0 + 8192), (LDS*)(dst0 + 8192),
                                         16, 0, 0);
    };

    // ---- prologue: A0, B0, B1 in flight; wait A0,B0 (leave B1 flying) ----
    stage(Xp, pbA, 0, 0, NP_A);
    stage(Zp, pbB, 0, 1, NP_B);
    stage(Zp, pbB, 1, 1, NP_B);
    asm volatile("s_waitcnt vmcnt(2)" ::: "memory");
    __builtin_amdgcn_s_barrier();

    bf16x8 af[4], bfr[4];

    #pragma unroll
    for (int t = 0; t < NKT; ++t) {
        const int buf = t & 1;
        const char* Ab = (const char*)Sh + buf * 32768 + lane * 16;

        // ---- ph0: read A m0-3 + B n0-3; stage A(t+1) into buf^1 ----
        #pragma unroll
        for (int m = 0; m < 4; ++m)
            af[m] = *(const bf16x8*)(Ab + (wr * 8 + m) * 1024);
        #pragma unroll
        for (int n = 0; n < 4; ++n)
            bfr[n] = *(const bf16x8*)(Ab + 16384 + (wc * 4 + n) * 1024);
        if (t + 1 < NKT) stage(Xp, pbA, t + 1, 0, NP_A);
        __builtin_amdgcn_s_barrier();
        asm volatile("s_waitcnt lgkmcnt(0)" ::: "memory");
        __builtin_amdgcn_sched_barrier(0);
        __builtin_amdgcn_s_setprio(1);
        #pragma unroll
        for (int m = 0; m < 4; ++m)
            #pragma unroll
            for (int n = 0; n < 4; ++n)
                acc[m][n] = __builtin_amdgcn_mfma_f32_16x16x32_bf16(
                    af[m], bfr[n], acc[m][n], 0, 0, 0);
        __builtin_amdgcn_s_setprio(0);
        __builtin_amdgcn_s_barrier();

        // ---- ph1: read A m4-7 (B reused from regs); stage B(t+2) ----
        #pragma unroll
        for (int m = 0; m < 4; ++m)
            af[m] = *(const bf16x8*)(Ab + (wr * 8 + 4 + m) * 1024);
        if (t + 2 < NKT) stage(Zp, pbB, t + 2, 1, NP_B);
        __builtin_amdgcn_s_barrier();
        asm volatile("s_waitcnt lgkmcnt(0)" ::: "memory");
        __builtin_amdgcn_sched_barrier(0);
        __builtin_amdgcn_s_setprio(1);
        #pragma unroll
        for (int m = 0; m < 4; ++m)
            #pragma unroll
            for (int n = 0; n < 4; ++n)
                acc[4 + m][n] = __builtin_amdgcn_mfma_f32_16x16x32_bf16(
                    af[m], bfr[n], acc[4 + m][n], 0, 0, 0);
        __builtin_amdgcn_s_setprio(0);

        // tile-boundary counted wait: newest stage (2 loads) may stay in flight
        if (t < NKT - 2) {
            asm volatile("s_waitcnt vmcnt(2)" ::: "memory");
            __builtin_amdgcn_s_barrier();
        } else if (t == NKT - 2) {
            asm volatile("s_waitcnt vmcnt(0)" ::: "memory");
            __builtin_amdgcn_s_barrier();
        }
    }

    // ---- fused RBF epilogue ----
    // C frag (16x16x32): col = lane&15, row = (lane>>4)*4 + reg  [m89]
    const int rg   = lane >> 4;
    const int lcol = lane & 15;

    float znv[4];
    #pragma unroll
    for (int n = 0; n < 4; ++n)
        znv[n] = zn[jBase + wc * 64 + n * 16 + lcol];

    float cs[4] = {0.f, 0.f, 0.f, 0.f};
    #pragma unroll
    for (int m = 0; m < 8; ++m) {
        float wv[4], xv[4];
        #pragma unroll
        for (int r = 0; r < 4; ++r) {
            const int i = iBase + wr * 128 + m * 16 + rg * 4 + r;
            wv[r] = w[i];
            xv[r] = xn[i];
        }
        #pragma unroll
        for (int n = 0; n < 4; ++n)
            #pragma unroll
            for (int r = 0; r < 4; ++r) {
                float d = xv[r] + znv[n] - 2.0f * acc[m][n][r];
                d = fmaxf(d, 0.0f);
                cs[n] += wv[r] * exp2f(C2EXP * d);
            }
    }

    #pragma unroll
    for (int n = 0; n < 4; ++n) {
        const int j = jBase + wc * 64 + n * 16 + lcol;
        float c = cs[n];
        c += __shfl_xor(c, 16);
        c += __shfl_xor(c, 32);
        if (lane < 16) atomicAdd(out + j, c);
    }
}

// ---------------- launch -----------------------------------------------------
extern "C" void kernel_launch(void* const* d_in, const int* in_sizes, int n_in,
                              void* d_out, int out_size, void* d_ws, size_t ws_size,
                              hipStream_t stream)
{
    const float* Z = (const float*)d_in[0];   // inputs [4096, 512]
    const float* X = (const float*)d_in[1];   // X      [8192, 512]
    const float* Y = (const float*)d_in[2];   // Y      [8192, 1]
    const float* a = (const float*)d_in[3];   // a      [8192, 1]
    const float* b = (const float*)d_in[4];   // b      [1, 1]
    float* out = (float*)d_out;               // [4096, 1]

    char* ws = (char*)d_ws;
    __bf16* Xp = (__bf16*)ws;                                   // 8 MB
    __bf16* Zp = (__bf16*)(ws + 8ull * 1024 * 1024);            // 4 MB
    float*  xn = (float*)(ws + 12ull * 1024 * 1024);            // 32 KB
    float*  zn = xn + N_SV;                                     // 16 KB
    float*  w  = zn + M_Q;                                      // 32 KB

    svm_prep<<<NP_A + NP_B, 256, 0, stream>>>(Z, X, Y, a, b, Xp, Zp, xn, zn, w, out);
    svm_main<<<dim3(M_Q / 256, N_SV / 256), 512, 0, stream>>>(Xp, Zp, xn, zn, w, out);
}